// Round 13
// baseline (129.791 us; speedup 1.0000x reference)
//
#include <hip/hip_runtime.h>

// Chamfer (single-directional) via split-fp16 MFMA, target-split waves,
// software-pipelined fold (fold tile t while tile t+1's MFMAs execute).
// d2(q,t) = x2(q) + [ -2 x.y + y2 ](q,t);  x2 added after the min over t.
// A = target fragments (rows), B = query fragments (cols): each lane's 16
// C elements are 16 target-rows of ONE query-col -> min folds in-register.
// Fold: pairwise min3-fusable accumulate into 8 persistent accumulators
// (v_e = fminf(fminf(c[2e],c[2e+1]), v_e)), final 8->1 tree once per kernel.
// K=16 slot scheme (HW-validated rounds 6/8/11, absmax 0.0):
//   k0-2: T=-2*yh Q=xh | k3-5: T=-2*yh/32 Q=32*xl | k6-8: T=-64*yl Q=xh/32
//   k9: T=y2h Q=1 | k10: T=32*y2l Q=1/32
// Structure: 512 thr = 8 waves; waves 0-3 -> target half 0, waves 4-7 ->
// half 1 (same queries). 8 passes x 64KB LDS (32 tiles/half). Fragments
// prebuilt into d_ws by a prep kernel (fallback: in-kernel rebuild).

typedef _Float16 half8 __attribute__((ext_vector_type(8)));
typedef float   f32x16 __attribute__((ext_vector_type(16)));

#define BB 8
#define NN 16384
#define MM 16384
#define THREADS 512
#define QT 2
#define Q_PER_BLOCK 256                    // 4 q-waves * QT * 32
#define QC_SPLIT (NN / Q_PER_BLOCK)        // 64
#define NPASS 8
#define HALF_UNITS 2048                    // 32 tiles * 64 half8 per half-buffer
#define WS_UNITS_PER_B 32768               // 512 tiles * 64
#define WS_BYTES ((size_t)BB * WS_UNITS_PER_B * 16)

// pairwise accumulate: 8 min3-fusable ops per 16-elem C tile
#define ACC8(c, a0,a1,a2,a3,a4,a5,a6,a7)                   \
    a0 = fminf(fminf((c)[0],  (c)[1]),  a0);               \
    a1 = fminf(fminf((c)[2],  (c)[3]),  a1);               \
    a2 = fminf(fminf((c)[4],  (c)[5]),  a2);               \
    a3 = fminf(fminf((c)[6],  (c)[7]),  a3);               \
    a4 = fminf(fminf((c)[8],  (c)[9]),  a4);               \
    a5 = fminf(fminf((c)[10], (c)[11]), a5);               \
    a6 = fminf(fminf((c)[12], (c)[13]), a6);               \
    a7 = fminf(fminf((c)[14], (c)[15]), a7);

__device__ inline void make_frags(float yx, float yy, float yz,
                                  half8& f0, half8& f1) {
    const float hx = (float)(_Float16)yx; const float lx = yx - hx;
    const float hy = (float)(_Float16)yy; const float ly = yy - hy;
    const float hz = (float)(_Float16)yz; const float lz = yz - hz;
    const float y2 = yx*yx + yy*yy + yz*yz;
    const float h2 = (float)(_Float16)y2; const float l2 = y2 - h2;
    f0[0] = (_Float16)(-2.f     * hx);
    f0[1] = (_Float16)(-2.f     * hy);
    f0[2] = (_Float16)(-2.f     * hz);
    f0[3] = (_Float16)(-0.0625f * hx);
    f0[4] = (_Float16)(-0.0625f * hy);
    f0[5] = (_Float16)(-0.0625f * hz);
    f0[6] = (_Float16)(-64.f    * lx);
    f0[7] = (_Float16)(-64.f    * ly);
    f1[0] = (_Float16)(-64.f    * lz);
    f1[1] = (_Float16)h2;
    f1[2] = (_Float16)(32.f     * l2);
    f1[3] = (_Float16)0.f; f1[4] = (_Float16)0.f;
    f1[5] = (_Float16)0.f; f1[6] = (_Float16)0.f; f1[7] = (_Float16)0.f;
}

__global__ __launch_bounds__(256)
void prep_kernel(const float* __restrict__ v, half8* __restrict__ wsf) {
    const int t  = blockIdx.x * 256 + threadIdx.x;   // [0, BB*MM)
    const int b  = t >> 14;
    const int ti = t & (MM - 1);
    const float* p = v + (size_t)b * MM * 3 + (size_t)ti * 3;
    half8 f0, f1;
    make_frags(p[0], p[1], p[2], f0, f1);
    const size_t base = (size_t)b * WS_UNITS_PER_B + (size_t)(ti >> 5) * 64 + (ti & 31);
    wsf[base]      = f0;
    wsf[base + 32] = f1;
}

template<int USE_WS>
__global__ __launch_bounds__(THREADS, 2)
void chamfer_kernel(const float* __restrict__ v,    // targets [B,M,3]
                    const float* __restrict__ vp,   // queries [B,N,3]
                    const half8* __restrict__ wsf,  // prebuilt fragments
                    float* __restrict__ out)
{
    __shared__ half8 shA[2 * HALF_UNITS];            // 64 KB

    const int tid  = threadIdx.x;
    const int lane = tid & 63;
    const int l31  = lane & 31;
    const int hi   = lane >> 5;
    const int wav  = tid >> 6;
    const int h    = wav >> 2;                       // target half
    const int qw   = wav & 3;                        // query wave id

    const int bx = blockIdx.x;
    const int qc = bx & (QC_SPLIT - 1);
    const int b  = bx >> 6;

    const float* vq = vp + (size_t)b * NN * 3;

    // ---------- build QT query fragments (B operand) ----------
    half8 b0, b1;
    float x20, x21;
    {
        const int qt0 = qc * (Q_PER_BLOCK / 32) + qw * QT;
#pragma unroll
        for (int j = 0; j < QT; ++j) {
            const int q = (qt0 + j) * 32 + l31;
            const float x = vq[q*3+0], y = vq[q*3+1], z = vq[q*3+2];
            const float hx = (float)(_Float16)x; const float lx = x - hx;
            const float hy = (float)(_Float16)y; const float ly = y - hy;
            const float hz = (float)(_Float16)z; const float lz = z - hz;
            const float x2 = x*x + y*y + z*z;
            half8 t_;
            if (hi == 0) {
                t_[0] = (_Float16)hx; t_[1] = (_Float16)hy; t_[2] = (_Float16)hz;
                t_[3] = (_Float16)(32.f * lx);
                t_[4] = (_Float16)(32.f * ly);
                t_[5] = (_Float16)(32.f * lz);
                t_[6] = (_Float16)(0.03125f * hx);
                t_[7] = (_Float16)(0.03125f * hy);
            } else {
                t_[0] = (_Float16)(0.03125f * hz);
                t_[1] = (_Float16)1.f;
                t_[2] = (_Float16)0.03125f;
                t_[3] = (_Float16)0.f; t_[4] = (_Float16)0.f;
                t_[5] = (_Float16)0.f; t_[6] = (_Float16)0.f; t_[7] = (_Float16)0.f;
            }
            if (j == 0) { b0 = t_; x20 = x2; } else { b1 = t_; x21 = x2; }
        }
    }

    f32x16 Z;
#pragma unroll
    for (int e = 0; e < 16; ++e) Z[e] = 0.f;

    // 8 persistent pairwise-min accumulators per query fragment
    float v0 = 3.4e38f, v1 = 3.4e38f, v2 = 3.4e38f, v3 = 3.4e38f;
    float v4 = 3.4e38f, v5 = 3.4e38f, v6 = 3.4e38f, v7 = 3.4e38f;
    float w0 = 3.4e38f, w1 = 3.4e38f, w2 = 3.4e38f, w3 = 3.4e38f;
    float w4 = 3.4e38f, w5 = 3.4e38f, w6 = 3.4e38f, w7 = 3.4e38f;

    const half8* tile_base = shA + h * HALF_UNITS;

    for (int pass = 0; pass < NPASS; ++pass) {
        __syncthreads();   // previous pass's reads complete before overwrite
        if constexpr (USE_WS) {
            const uint4* g = (const uint4*)wsf + (size_t)b * WS_UNITS_PER_B;
            uint4* s = (uint4*)shA;
#pragma unroll
            for (int k = 0; k < 4; ++k)          // half 0
                s[tid + k * THREADS] = g[pass * 2048 + tid + k * THREADS];
#pragma unroll
            for (int k = 0; k < 4; ++k)          // half 1
                s[2048 + tid + k * THREADS] = g[16384 + pass * 2048 + tid + k * THREADS];
        } else {
            const float* vb = v + (size_t)b * MM * 3;
#pragma unroll
            for (int k = 0; k < 4; ++k) {
                const int tl    = tid + k * THREADS;       // [0,2048)
                const int hh    = tl >> 10;
                const int local = tl & 1023;
                const int t     = hh * 8192 + pass * 1024 + local;
                half8 f0, f1;
                make_frags(vb[t*3+0], vb[t*3+1], vb[t*3+2], f0, f1);
                const int unit = hh * HALF_UNITS + (local >> 5) * 64 + (local & 31);
                shA[unit]      = f0;
                shA[unit + 32] = f1;
            }
        }
        __syncthreads();

        // ---------- software-pipelined: fold tile t under tile t+1's MFMAs ----------
        half8 fA = tile_base[lane];
        f32x16 pA0 = __builtin_amdgcn_mfma_f32_32x32x16_f16(fA, b0, Z, 0, 0, 0);
        f32x16 pA1 = __builtin_amdgcn_mfma_f32_32x32x16_f16(fA, b1, Z, 0, 0, 0);

        for (int tt = 0; tt < 30; tt += 2) {
            const half8 fB = tile_base[(tt + 1) * 64 + lane];
            const f32x16 pB0 = __builtin_amdgcn_mfma_f32_32x32x16_f16(fB, b0, Z, 0, 0, 0);
            const f32x16 pB1 = __builtin_amdgcn_mfma_f32_32x32x16_f16(fB, b1, Z, 0, 0, 0);
            ACC8(pA0, v0, v1, v2, v3, v4, v5, v6, v7)
            ACC8(pA1, w0, w1, w2, w3, w4, w5, w6, w7)
            fA = tile_base[(tt + 2) * 64 + lane];
            pA0 = __builtin_amdgcn_mfma_f32_32x32x16_f16(fA, b0, Z, 0, 0, 0);
            pA1 = __builtin_amdgcn_mfma_f32_32x32x16_f16(fA, b1, Z, 0, 0, 0);
            ACC8(pB0, v0, v1, v2, v3, v4, v5, v6, v7)
            ACC8(pB1, w0, w1, w2, w3, w4, w5, w6, w7)
        }
        // tail: pA holds tile 30; tile 31 remains
        {
            const half8 fB = tile_base[31 * 64 + lane];
            const f32x16 pB0 = __builtin_amdgcn_mfma_f32_32x32x16_f16(fB, b0, Z, 0, 0, 0);
            const f32x16 pB1 = __builtin_amdgcn_mfma_f32_32x32x16_f16(fB, b1, Z, 0, 0, 0);
            ACC8(pA0, v0, v1, v2, v3, v4, v5, v6, v7)
            ACC8(pA1, w0, w1, w2, w3, w4, w5, w6, w7)
            ACC8(pB0, v0, v1, v2, v3, v4, v5, v6, v7)
            ACC8(pB1, w0, w1, w2, w3, w4, w5, w6, w7)
        }
    }

    // ---------- final 8->1 trees (once per kernel) ----------
    float r0 = fminf(fminf(fminf(v0, v1), fminf(v2, v3)),
                     fminf(fminf(v4, v5), fminf(v6, v7)));
    float r1 = fminf(fminf(fminf(w0, w1), fminf(w2, w3)),
                     fminf(fminf(w4, w5), fminf(w6, w7)));

    // ---------- merge target halves across wave pairs, then reduce ----------
    __syncthreads();
    float* fs = (float*)shA;
    fs[wav * 128 + lane]      = r0;
    fs[wav * 128 + 64 + lane] = r1;
    __syncthreads();
    if (wav < 4) {
        r0 = fminf(fs[wav * 128 + lane],      fs[(wav + 4) * 128 + lane]);
        r1 = fminf(fs[wav * 128 + 64 + lane], fs[(wav + 4) * 128 + 64 + lane]);
        const float m0 = fminf(r0, __shfl_xor(r0, 32, 64));
        const float m1 = fminf(r1, __shfl_xor(r1, 32, 64));
        const float d0 = fmaxf(m0 + x20, 0.f);
        const float d1 = fmaxf(m1 + x21, 0.f);
        float s = (hi == 0) ? (d0 + d1) : 0.f;
#pragma unroll
        for (int off = 32; off; off >>= 1) s += __shfl_down(s, off, 64);
        if (lane == 0) fs[1024 + wav] = s;
    }
    __syncthreads();
    if (tid == 0) {
        const float t = fs[1024] + fs[1025] + fs[1026] + fs[1027];
        atomicAdd(out, t * (1.0f / ((float)BB * (float)NN)));
    }
}

extern "C" void kernel_launch(void* const* d_in, const int* in_sizes, int n_in,
                              void* d_out, int out_size, void* d_ws, size_t ws_size,
                              hipStream_t stream) {
    const float* v  = (const float*)d_in[0];   // targets
    const float* vp = (const float*)d_in[1];   // queries
    float* out = (float*)d_out;

    hipMemsetAsync(out, 0, sizeof(float), stream);
    if (ws_size >= WS_BYTES) {
        half8* wsf = (half8*)d_ws;
        prep_kernel<<<(BB * MM) / 256, 256, 0, stream>>>(v, wsf);
        chamfer_kernel<1><<<BB * QC_SPLIT, THREADS, 0, stream>>>(v, vp, wsf, out);
    } else {
        chamfer_kernel<0><<<BB * QC_SPLIT, THREADS, 0, stream>>>(v, vp, nullptr, out);
    }
}

// Round 16
// 125.593 us; speedup vs baseline: 1.0334x; 1.0334x over previous
//
#include <hip/hip_runtime.h>

// Chamfer (single-directional) via split-fp16 MFMA, target-split waves,
// software-pipelined fold, VGPR-pinned C-tiles.
// d2(q,t) = x2(q) + [ -2 x.y + y2 ](q,t);  x2 added after the min over t.
// A = target fragments (rows), B = query fragments (cols): each lane's 16
// C elements are 16 target-rows of ONE query-col -> min folds in-register.
// Fold: pairwise min3-fusable accumulate into 8 persistent accumulators.
// PIN_V: empty asm "+v" constraint on each C-tile before its fold forces
// regalloc to place the MFMA D in arch VGPRs (round 13: AGPR allocation
// cost ~16 v_accvgpr_read per MFMA = 2/3 of all VALU issue).
// K=16 slot scheme (HW-validated rounds 6/8/11/13, absmax 0.0):
//   k0-2: T=-2*yh Q=xh | k3-5: T=-2*yh/32 Q=32*xl | k6-8: T=-64*yl Q=xh/32
//   k9: T=y2h Q=1 | k10: T=32*y2l Q=1/32
// Structure: 512 thr = 8 waves; waves 0-3 -> target half 0, waves 4-7 ->
// half 1 (same queries). 8 passes x 64KB LDS (32 tiles/half). Fragments
// prebuilt into d_ws by a prep kernel (fallback: in-kernel rebuild).

typedef _Float16 half8 __attribute__((ext_vector_type(8)));
typedef float   f32x16 __attribute__((ext_vector_type(16)));

#define BB 8
#define NN 16384
#define MM 16384
#define THREADS 512
#define QT 2
#define Q_PER_BLOCK 256                    // 4 q-waves * QT * 32
#define QC_SPLIT (NN / Q_PER_BLOCK)        // 64
#define NPASS 8
#define HALF_UNITS 2048                    // 32 tiles * 64 half8 per half-buffer
#define WS_UNITS_PER_B 32768               // 512 tiles * 64
#define WS_BYTES ((size_t)BB * WS_UNITS_PER_B * 16)

#define PIN_V(x) asm volatile("" : "+v"(x))

// pairwise accumulate: 8 min3-fusable ops per 16-elem C tile
#define ACC8(c, a0,a1,a2,a3,a4,a5,a6,a7)                   \
    a0 = fminf(fminf((c)[0],  (c)[1]),  a0);               \
    a1 = fminf(fminf((c)[2],  (c)[3]),  a1);               \
    a2 = fminf(fminf((c)[4],  (c)[5]),  a2);               \
    a3 = fminf(fminf((c)[6],  (c)[7]),  a3);               \
    a4 = fminf(fminf((c)[8],  (c)[9]),  a4);               \
    a5 = fminf(fminf((c)[10], (c)[11]), a5);               \
    a6 = fminf(fminf((c)[12], (c)[13]), a6);               \
    a7 = fminf(fminf((c)[14], (c)[15]), a7);

__device__ inline void make_frags(float yx, float yy, float yz,
                                  half8& f0, half8& f1) {
    const float hx = (float)(_Float16)yx; const float lx = yx - hx;
    const float hy = (float)(_Float16)yy; const float ly = yy - hy;
    const float hz = (float)(_Float16)yz; const float lz = yz - hz;
    const float y2 = yx*yx + yy*yy + yz*yz;
    const float h2 = (float)(_Float16)y2; const float l2 = y2 - h2;
    f0[0] = (_Float16)(-2.f     * hx);
    f0[1] = (_Float16)(-2.f     * hy);
    f0[2] = (_Float16)(-2.f     * hz);
    f0[3] = (_Float16)(-0.0625f * hx);
    f0[4] = (_Float16)(-0.0625f * hy);
    f0[5] = (_Float16)(-0.0625f * hz);
    f0[6] = (_Float16)(-64.f    * lx);
    f0[7] = (_Float16)(-64.f    * ly);
    f1[0] = (_Float16)(-64.f    * lz);
    f1[1] = (_Float16)h2;
    f1[2] = (_Float16)(32.f     * l2);
    f1[3] = (_Float16)0.f; f1[4] = (_Float16)0.f;
    f1[5] = (_Float16)0.f; f1[6] = (_Float16)0.f; f1[7] = (_Float16)0.f;
}

__global__ __launch_bounds__(256)
void prep_kernel(const float* __restrict__ v, half8* __restrict__ wsf) {
    const int t  = blockIdx.x * 256 + threadIdx.x;   // [0, BB*MM)
    const int b  = t >> 14;
    const int ti = t & (MM - 1);
    const float* p = v + (size_t)b * MM * 3 + (size_t)ti * 3;
    half8 f0, f1;
    make_frags(p[0], p[1], p[2], f0, f1);
    const size_t base = (size_t)b * WS_UNITS_PER_B + (size_t)(ti >> 5) * 64 + (ti & 31);
    wsf[base]      = f0;
    wsf[base + 32] = f1;
}

template<int USE_WS>
__global__ __launch_bounds__(THREADS)
void chamfer_kernel(const float* __restrict__ v,    // targets [B,M,3]
                    const float* __restrict__ vp,   // queries [B,N,3]
                    const half8* __restrict__ wsf,  // prebuilt fragments
                    float* __restrict__ out)
{
    __shared__ half8 shA[2 * HALF_UNITS];            // 64 KB

    const int tid  = threadIdx.x;
    const int lane = tid & 63;
    const int l31  = lane & 31;
    const int hi   = lane >> 5;
    const int wav  = tid >> 6;
    const int h    = wav >> 2;                       // target half
    const int qw   = wav & 3;                        // query wave id

    const int bx = blockIdx.x;
    const int qc = bx & (QC_SPLIT - 1);
    const int b  = bx >> 6;

    const float* vq = vp + (size_t)b * NN * 3;

    // ---------- build QT query fragments (B operand) ----------
    half8 b0, b1;
    float x20, x21;
    {
        const int qt0 = qc * (Q_PER_BLOCK / 32) + qw * QT;
#pragma unroll
        for (int j = 0; j < QT; ++j) {
            const int q = (qt0 + j) * 32 + l31;
            const float x = vq[q*3+0], y = vq[q*3+1], z = vq[q*3+2];
            const float hx = (float)(_Float16)x; const float lx = x - hx;
            const float hy = (float)(_Float16)y; const float ly = y - hy;
            const float hz = (float)(_Float16)z; const float lz = z - hz;
            const float x2 = x*x + y*y + z*z;
            half8 t_;
            if (hi == 0) {
                t_[0] = (_Float16)hx; t_[1] = (_Float16)hy; t_[2] = (_Float16)hz;
                t_[3] = (_Float16)(32.f * lx);
                t_[4] = (_Float16)(32.f * ly);
                t_[5] = (_Float16)(32.f * lz);
                t_[6] = (_Float16)(0.03125f * hx);
                t_[7] = (_Float16)(0.03125f * hy);
            } else {
                t_[0] = (_Float16)(0.03125f * hz);
                t_[1] = (_Float16)1.f;
                t_[2] = (_Float16)0.03125f;
                t_[3] = (_Float16)0.f; t_[4] = (_Float16)0.f;
                t_[5] = (_Float16)0.f; t_[6] = (_Float16)0.f; t_[7] = (_Float16)0.f;
            }
            if (j == 0) { b0 = t_; x20 = x2; } else { b1 = t_; x21 = x2; }
        }
    }

    f32x16 Z;
#pragma unroll
    for (int e = 0; e < 16; ++e) Z[e] = 0.f;

    // 8 persistent pairwise-min accumulators per query fragment
    float v0 = 3.4e38f, v1 = 3.4e38f, v2 = 3.4e38f, v3 = 3.4e38f;
    float v4 = 3.4e38f, v5 = 3.4e38f, v6 = 3.4e38f, v7 = 3.4e38f;
    float w0 = 3.4e38f, w1 = 3.4e38f, w2 = 3.4e38f, w3 = 3.4e38f;
    float w4 = 3.4e38f, w5 = 3.4e38f, w6 = 3.4e38f, w7 = 3.4e38f;

    const half8* tile_base = shA + h * HALF_UNITS;

    for (int pass = 0; pass < NPASS; ++pass) {
        __syncthreads();   // previous pass's reads complete before overwrite
        if constexpr (USE_WS) {
            const uint4* g = (const uint4*)wsf + (size_t)b * WS_UNITS_PER_B;
            uint4* s = (uint4*)shA;
#pragma unroll
            for (int k = 0; k < 4; ++k)          // half 0
                s[tid + k * THREADS] = g[pass * 2048 + tid + k * THREADS];
#pragma unroll
            for (int k = 0; k < 4; ++k)          // half 1
                s[2048 + tid + k * THREADS] = g[16384 + pass * 2048 + tid + k * THREADS];
        } else {
            const float* vb = v + (size_t)b * MM * 3;
#pragma unroll
            for (int k = 0; k < 4; ++k) {
                const int tl    = tid + k * THREADS;       // [0,2048)
                const int hh    = tl >> 10;
                const int local = tl & 1023;
                const int t     = hh * 8192 + pass * 1024 + local;
                half8 f0, f1;
                make_frags(vb[t*3+0], vb[t*3+1], vb[t*3+2], f0, f1);
                const int unit = hh * HALF_UNITS + (local >> 5) * 64 + (local & 31);
                shA[unit]      = f0;
                shA[unit + 32] = f1;
            }
        }
        __syncthreads();

        // ---------- software-pipelined: fold tile t under tile t+1's MFMAs ----------
        half8 fA = tile_base[lane];
        f32x16 pA0 = __builtin_amdgcn_mfma_f32_32x32x16_f16(fA, b0, Z, 0, 0, 0);
        f32x16 pA1 = __builtin_amdgcn_mfma_f32_32x32x16_f16(fA, b1, Z, 0, 0, 0);

        for (int tt = 0; tt < 30; tt += 2) {
            const half8 fB = tile_base[(tt + 1) * 64 + lane];
            f32x16 pB0 = __builtin_amdgcn_mfma_f32_32x32x16_f16(fB, b0, Z, 0, 0, 0);
            f32x16 pB1 = __builtin_amdgcn_mfma_f32_32x32x16_f16(fB, b1, Z, 0, 0, 0);
            PIN_V(pA0);
            PIN_V(pA1);
            ACC8(pA0, v0, v1, v2, v3, v4, v5, v6, v7)
            ACC8(pA1, w0, w1, w2, w3, w4, w5, w6, w7)
            fA = tile_base[(tt + 2) * 64 + lane];
            pA0 = __builtin_amdgcn_mfma_f32_32x32x16_f16(fA, b0, Z, 0, 0, 0);
            pA1 = __builtin_amdgcn_mfma_f32_32x32x16_f16(fA, b1, Z, 0, 0, 0);
            PIN_V(pB0);
            PIN_V(pB1);
            ACC8(pB0, v0, v1, v2, v3, v4, v5, v6, v7)
            ACC8(pB1, w0, w1, w2, w3, w4, w5, w6, w7)
        }
        // tail: pA holds tile 30; tile 31 remains
        {
            const half8 fB = tile_base[31 * 64 + lane];
            f32x16 pB0 = __builtin_amdgcn_mfma_f32_32x32x16_f16(fB, b0, Z, 0, 0, 0);
            f32x16 pB1 = __builtin_amdgcn_mfma_f32_32x32x16_f16(fB, b1, Z, 0, 0, 0);
            PIN_V(pA0);
            PIN_V(pA1);
            ACC8(pA0, v0, v1, v2, v3, v4, v5, v6, v7)
            ACC8(pA1, w0, w1, w2, w3, w4, w5, w6, w7)
            PIN_V(pB0);
            PIN_V(pB1);
            ACC8(pB0, v0, v1, v2, v3, v4, v5, v6, v7)
            ACC8(pB1, w0, w1, w2, w3, w4, w5, w6, w7)
        }
    }

    // ---------- final 8->1 trees (once per kernel) ----------
    float r0 = fminf(fminf(fminf(v0, v1), fminf(v2, v3)),
                     fminf(fminf(v4, v5), fminf(v6, v7)));
    float r1 = fminf(fminf(fminf(w0, w1), fminf(w2, w3)),
                     fminf(fminf(w4, w5), fminf(w6, w7)));

    // ---------- merge target halves across wave pairs, then reduce ----------
    __syncthreads();
    float* fs = (float*)shA;
    fs[wav * 128 + lane]      = r0;
    fs[wav * 128 + 64 + lane] = r1;
    __syncthreads();
    if (wav < 4) {
        r0 = fminf(fs[wav * 128 + lane],      fs[(wav + 4) * 128 + lane]);
        r1 = fminf(fs[wav * 128 + 64 + lane], fs[(wav + 4) * 128 + 64 + lane]);
        const float m0 = fminf(r0, __shfl_xor(r0, 32, 64));
        const float m1 = fminf(r1, __shfl_xor(r1, 32, 64));
        const float d0 = fmaxf(m0 + x20, 0.f);
        const float d1 = fmaxf(m1 + x21, 0.f);
        float s = (hi == 0) ? (d0 + d1) : 0.f;
#pragma unroll
        for (int off = 32; off; off >>= 1) s += __shfl_down(s, off, 64);
        if (lane == 0) fs[1024 + wav] = s;
    }
    __syncthreads();
    if (tid == 0) {
        const float t = fs[1024] + fs[1025] + fs[1026] + fs[1027];
        atomicAdd(out, t * (1.0f / ((float)BB * (float)NN)));
    }
}

extern "C" void kernel_launch(void* const* d_in, const int* in_sizes, int n_in,
                              void* d_out, int out_size, void* d_ws, size_t ws_size,
                              hipStream_t stream) {
    const float* v  = (const float*)d_in[0];   // targets
    const float* vp = (const float*)d_in[1];   // queries
    float* out = (float*)d_out;

    hipMemsetAsync(out, 0, sizeof(float), stream);
    if (ws_size >= WS_BYTES) {
        half8* wsf = (half8*)d_ws;
        prep_kernel<<<(BB * MM) / 256, 256, 0, stream>>>(v, wsf);
        chamfer_kernel<1><<<BB * QC_SPLIT, THREADS, 0, stream>>>(v, vp, wsf, out);
    } else {
        chamfer_kernel<0><<<BB * QC_SPLIT, THREADS, 0, stream>>>(v, vp, nullptr, out);
    }
}